// Round 1
// 599.516 us; speedup vs baseline: 1.0351x; 1.0351x over previous
//
#include <hip/hip_runtime.h>
#include <hip/hip_bf16.h>

// ---------- helpers ----------
typedef __attribute__((ext_vector_type(8))) __bf16 bf16x8;
typedef __attribute__((ext_vector_type(4))) float f32x4;

__device__ __forceinline__ float b2f(unsigned short u) {
    unsigned int x = ((unsigned int)u) << 16;
    float f;
    __builtin_memcpy(&f, &x, 4);
    return f;
}
__device__ __forceinline__ unsigned short f2b(float f) {
    __hip_bfloat16 h = __float2bfloat16(f);
    unsigned short u;
    __builtin_memcpy(&u, &h, 2);
    return u;
}
union U4 { uint4 v; unsigned short u[8]; };

// ---------- 512x512 transpose + f32->bf16 convert (for W matrices) ----------
__global__ __launch_bounds__(256) void transpose512cvt(const float* __restrict__ in,
                                                       unsigned short* __restrict__ out)
{
    __shared__ float tile[32][33];
    int tx = threadIdx.x & 31, ty = threadIdx.x >> 5;
    int bx = blockIdx.x, by = blockIdx.y;
    #pragma unroll
    for (int i = 0; i < 32; i += 8)
        tile[ty + i][tx] = in[(size_t)(bx * 32 + ty + i) * 512 + by * 32 + tx];
    __syncthreads();
    #pragma unroll
    for (int i = 0; i < 32; i += 8)
        out[(size_t)(by * 32 + ty + i) * 512 + bx * 32 + tx] = f2b(tile[tx][ty + i]);
}

// ---------- GEMM 128x128 tile (m93-style): C = A[M,512] @ Bt[512,N]^T + bias ----------
// 256 threads = 4 waves in 2x2; each wave owns 64x64 = 4x4 MFMA tiles.
// CMODE: 0 = f32 token-major, 1 = bf16 token-major, 2 = bf16 head-major [b][h][n][d]
#define GPAD 40  // row stride in elems (32 + 8 pad, 80 B, 16B-aligned)

template<bool AF32, int CMODE>
__global__ __launch_bounds__(256) void gemm128(
    const void* __restrict__ Av,
    const unsigned short* __restrict__ Bt,
    const float* __restrict__ bias,
    void* __restrict__ Cv,
    int M, int N)
{
    const int K = 512;
    __shared__ __align__(16) unsigned short As[128 * GPAD];
    __shared__ __align__(16) unsigned short Bs[128 * GPAD];
    int m0 = blockIdx.x * 128, n0 = blockIdx.y * 128;
    int t = threadIdx.x;
    int wave = t >> 6, lane = t & 63, quad = lane >> 4, l16 = lane & 15;
    int wr = wave >> 1, wc = wave & 1;

    f32x4 acc[4][4];
    #pragma unroll
    for (int i = 0; i < 4; ++i)
        #pragma unroll
        for (int j = 0; j < 4; ++j) acc[i][j] = (f32x4){0.f, 0.f, 0.f, 0.f};

    int r = t >> 1, half = (t & 1) * 16;  // staging: row r, elems half..half+16

    for (int k0 = 0; k0 < K; k0 += 32) {
        U4 a0, a1;
        uint4 b0, b1;
        if constexpr (AF32) {
            const float* Ap = (const float*)Av + (size_t)(m0 + r) * K + k0 + half;
            float4 f0 = ((const float4*)Ap)[0], f1 = ((const float4*)Ap)[1];
            float4 f2 = ((const float4*)Ap)[2], f3 = ((const float4*)Ap)[3];
            a0.u[0]=f2b(f0.x); a0.u[1]=f2b(f0.y); a0.u[2]=f2b(f0.z); a0.u[3]=f2b(f0.w);
            a0.u[4]=f2b(f1.x); a0.u[5]=f2b(f1.y); a0.u[6]=f2b(f1.z); a0.u[7]=f2b(f1.w);
            a1.u[0]=f2b(f2.x); a1.u[1]=f2b(f2.y); a1.u[2]=f2b(f2.z); a1.u[3]=f2b(f2.w);
            a1.u[4]=f2b(f3.x); a1.u[5]=f2b(f3.y); a1.u[6]=f2b(f3.z); a1.u[7]=f2b(f3.w);
        } else {
            const unsigned short* Ap = (const unsigned short*)Av + (size_t)(m0 + r) * K + k0 + half;
            a0.v = ((const uint4*)Ap)[0];
            a1.v = ((const uint4*)Ap)[1];
        }
        {
            const unsigned short* Bp = Bt + (size_t)(n0 + r) * K + k0 + half;
            b0 = ((const uint4*)Bp)[0];
            b1 = ((const uint4*)Bp)[1];
        }
        __syncthreads();
        *(uint4*)&As[r * GPAD + half] = a0.v;
        *(uint4*)&As[r * GPAD + half + 8] = a1.v;
        *(uint4*)&Bs[r * GPAD + half] = b0;
        *(uint4*)&Bs[r * GPAD + half + 8] = b1;
        __syncthreads();
        bf16x8 af[4], bf[4];
        #pragma unroll
        for (int i = 0; i < 4; ++i)
            af[i] = *(const bf16x8*)&As[(wr * 64 + i * 16 + l16) * GPAD + quad * 8];
        #pragma unroll
        for (int j = 0; j < 4; ++j)
            bf[j] = *(const bf16x8*)&Bs[(wc * 64 + j * 16 + l16) * GPAD + quad * 8];
        #pragma unroll
        for (int i = 0; i < 4; ++i)
            #pragma unroll
            for (int j = 0; j < 4; ++j)
                acc[i][j] = __builtin_amdgcn_mfma_f32_16x16x32_bf16(af[i], bf[j], acc[i][j], 0, 0, 0);
    }
    // epilogue. C/D layout: col = lane&15, row = quad*4 + reg
    #pragma unroll
    for (int i = 0; i < 4; ++i) {
        #pragma unroll
        for (int j = 0; j < 4; ++j) {
            int row = m0 + wr * 64 + i * 16 + quad * 4;
            int col = n0 + wc * 64 + j * 16 + l16;
            float bc = bias[col];
            #pragma unroll
            for (int ii = 0; ii < 4; ++ii) {
                float v = acc[i][j][ii] + bc;
                int R = row + ii;
                if constexpr (CMODE == 0) {
                    ((float*)Cv)[(size_t)R * N + col] = v;
                } else if constexpr (CMODE == 1) {
                    ((unsigned short*)Cv)[(size_t)R * N + col] = f2b(v);
                } else {
                    int bb = R >> 12, n = R & 4095, hh = col >> 6, d = col & 63;
                    ((unsigned short*)Cv)[(((size_t)bb * 8 + hh) * 4096 + n) * 64 + d] = f2b(v);
                }
            }
        }
    }
}

// ---------- temporal attention v2: MFMA, one block per (b, s-pair), 8 waves = 8 heads ----------
// Pair two adjacent s values -> Q tile 16x64 (rows = 2s x 8m), K tile 32x64
// (keys 0-7: s0 temporal, 8-15: s1 temporal, 16-31: static). Cross-s terms masked -inf.
// Per-wave-private LDS (V^T for PV B-operand, P round-trip) -> no barriers at all.
__global__ __launch_bounds__(512) void temporal_attn(
    const unsigned short* __restrict__ Qt, const unsigned short* __restrict__ KH,
    const unsigned short* __restrict__ VH, const unsigned short* __restrict__ Ksp,
    const unsigned short* __restrict__ Vsp,
    const int* __restrict__ mask_t, const int* __restrict__ mask_s,
    float* __restrict__ w_t_out, unsigned short* __restrict__ qkv_t)
{
    int blk = blockIdx.x;              // b*256 + sp
    int b = blk >> 8, sp = blk & 255;
    int s0 = sp * 2;
    int t = threadIdx.x;
    int h = t >> 6, lane = t & 63, quad = lane >> 4, l16 = lane & 15;

    __shared__ __align__(16) unsigned short Vt[8][64 * 40];  // per-head V^T [d][key(32)+pad]
    __shared__ __align__(16) unsigned short Pl[8][16 * 40];  // per-head P  [q][key(32)+pad]

    size_t bh = (size_t)(b * 8 + h);
    size_t tok0 = ((size_t)(b * 512 + s0)) * 8;  // first token row of the pair (rows 0..15 contiguous)

    // ---- stage V^T (wave-private; keys 0-15 temporal, 16-31 static) ----
    {
        int r = lane & 31, dh = (lane >> 5) * 32;
        const unsigned short* src = (r < 16)
            ? VH + (bh * 4096 + (size_t)(s0 * 8 + r)) * 64 + dh
            : Vsp + ((size_t)(b * 16 + (r - 16))) * 512 + h * 64 + dh;
        U4 u[4];
        #pragma unroll
        for (int g = 0; g < 4; ++g) u[g].v = ((const uint4*)src)[g];
        unsigned short* dst = &Vt[h][0];
        #pragma unroll
        for (int g = 0; g < 4; ++g)
            #pragma unroll
            for (int ii = 0; ii < 8; ++ii)
                dst[(dh + g * 8 + ii) * 40 + r] = u[g].u[ii];
    }

    // ---- Q / K fragments straight from global (row-major matches A/B fragment layout) ----
    const unsigned short* qp = Qt + (tok0 + l16) * 512 + h * 64 + quad * 8;
    bf16x8 qf0 = *(const bf16x8*)qp;
    bf16x8 qf1 = *(const bf16x8*)(qp + 32);
    const unsigned short* kpt = KH + (bh * 4096 + (size_t)(s0 * 8 + l16)) * 64 + quad * 8;
    bf16x8 kt0 = *(const bf16x8*)kpt;
    bf16x8 kt1 = *(const bf16x8*)(kpt + 32);
    const unsigned short* kps = Ksp + ((size_t)(b * 16 + l16)) * 512 + h * 64 + quad * 8;
    bf16x8 ks0 = *(const bf16x8*)kps;
    bf16x8 ks1 = *(const bf16x8*)(kps + 32);

    // ---- scores: C[row=q (quad*4+i)][col=key (l16)] ----
    f32x4 sc0 = (f32x4){0.f, 0.f, 0.f, 0.f};
    f32x4 sc1 = (f32x4){0.f, 0.f, 0.f, 0.f};
    sc0 = __builtin_amdgcn_mfma_f32_16x16x32_bf16(qf0, kt0, sc0, 0, 0, 0);
    sc0 = __builtin_amdgcn_mfma_f32_16x16x32_bf16(qf1, kt1, sc0, 0, 0, 0);
    sc1 = __builtin_amdgcn_mfma_f32_16x16x32_bf16(qf0, ks0, sc1, 0, 0, 0);
    sc1 = __builtin_amdgcn_mfma_f32_16x16x32_bf16(qf1, ks1, sc1, 0, 0, 0);

    // masks: tile0 key l16 maps linearly to token tok0+l16; cross-s block masked out.
    float madd0 = mask_t[tok0 + l16] ? 0.f : -1e30f;
    bool v0 = ((quad < 2) == (l16 < 8));   // row<8 <-> keys 0-7 (s0); row>=8 <-> keys 8-15 (s1)
    if (!v0) madd0 = -1e30f;
    float madd1 = mask_s[b * 16 + l16] ? 0.f : -1e30f;

    // ---- softmax per row (row lives entirely in one 16-lane quad group) ----
    float w0[4], w1[4];
    #pragma unroll
    for (int i = 0; i < 4; ++i) {
        float a = sc0[i] * 0.125f + madd0;
        float c = sc1[i] * 0.125f + madd1;
        float mx = fmaxf(a, c);
        mx = fmaxf(mx, __shfl_xor(mx, 1));
        mx = fmaxf(mx, __shfl_xor(mx, 2));
        mx = fmaxf(mx, __shfl_xor(mx, 4));
        mx = fmaxf(mx, __shfl_xor(mx, 8));
        float e0 = __expf(a - mx), e1 = __expf(c - mx);
        float se = e0 + e1;
        se += __shfl_xor(se, 1);
        se += __shfl_xor(se, 2);
        se += __shfl_xor(se, 4);
        se += __shfl_xor(se, 8);
        float inv = 1.f / se;
        w0[i] = e0 * inv;
        w1[i] = e1 * inv;
    }

    // ---- write w_t + stage P (wave-private LDS; masked entries are exactly 0) ----
    int row0 = quad * 4;
    #pragma unroll
    for (int i = 0; i < 4; ++i) {
        int row = row0 + i;
        Pl[h][row * 40 + l16] = f2b(w0[i]);
        Pl[h][row * 40 + 16 + l16] = f2b(w1[i]);
        int s = s0 + (row >> 3), m = row & 7;
        size_t wb = ((((size_t)b * 8 + h) * 512 + s) * 8 + m) * 24;
        if (v0) w_t_out[wb + (l16 & 7)] = w0[i];
        w_t_out[wb + 8 + l16] = w1[i];
    }

    // ---- PV: C[q][d] = P[16x32] . V[32x64]; K=32 fits one mfma k-step ----
    bf16x8 pa = *(const bf16x8*)&Pl[h][l16 * 40 + quad * 8];
    f32x4 oacc[4];
    #pragma unroll
    for (int j = 0; j < 4; ++j) {
        bf16x8 vb = *(const bf16x8*)&Vt[h][(j * 16 + l16) * 40 + quad * 8];
        oacc[j] = (f32x4){0.f, 0.f, 0.f, 0.f};
        oacc[j] = __builtin_amdgcn_mfma_f32_16x16x32_bf16(pa, vb, oacc[j], 0, 0, 0);
    }
    #pragma unroll
    for (int j = 0; j < 4; ++j)
        #pragma unroll
        for (int ii = 0; ii < 4; ++ii) {
            int row = quad * 4 + ii;
            qkv_t[(tok0 + row) * 512 + h * 64 + j * 16 + l16] = f2b(oacc[j][ii]);
        }
}

// ---------- static attention S1: fused scores + exp + PV, chunked ----------
// grid = 8 chunks x 64 (b,h). Keys processed in 32-wide steps; 129 steps total
// (step 128 = the 16 static keys). No max-subtraction (|s| <= ~8, exp safe in f32).
__global__ __launch_bounds__(256) void static_attn_s1(
    const unsigned short* __restrict__ Qsp, const unsigned short* __restrict__ KH,
    const unsigned short* __restrict__ VH, const unsigned short* __restrict__ Ksp,
    const unsigned short* __restrict__ Vsp,
    const int* __restrict__ mask_t, const int* __restrict__ mask_s,
    float* __restrict__ w_s, float* __restrict__ Ppart, float* __restrict__ Lpart)
{
    int blk = blockIdx.x;
    int bh = blk & 63, c = blk >> 6;
    int b = bh >> 3, h = bh & 7;
    __shared__ __align__(16) unsigned short Klds[32 * 72];  // [key][64] (+pad)
    __shared__ __align__(16) unsigned short Vlds[64 * 40];  // [d][key]  (+pad)
    __shared__ __align__(16) unsigned short Plds[16 * 40];  // [q][key]  (+pad)
    __shared__ float maskv[32];
    __shared__ float sL[2][16];
    int t = threadIdx.x, wave = t >> 6, lane = t & 63, quad = lane >> 4, l16 = lane & 15;

    // Q fragments (A-operand: m=l16 -> q, k=quad*8+j -> d)
    bf16x8 qf0 = *(const bf16x8*)(Qsp + ((size_t)(b * 16 + l16)) * 512 + h * 64 + quad * 8);
    bf16x8 qf1 = *(const bf16x8*)(Qsp + ((size_t)(b * 16 + l16)) * 512 + h * 64 + 32 + quad * 8);

    f32x4 pacc = (f32x4){0.f, 0.f, 0.f, 0.f};
    float Lacc[4] = {0.f, 0.f, 0.f, 0.f};
    int d0 = wave * 16;
    int sub = wave >> 1;
    int sr = t >> 3, spart = t & 7;
    int s0 = c * 16, s1 = (c == 7) ? 129 : (s0 + 16);

    for (int st = s0; st < s1; ++st) {
        int key0 = st * 32;
        // ---- stage K row-major, V transposed, masks ----
        int kk = key0 + sr;
        uint4 kv = {0, 0, 0, 0}, vv = {0, 0, 0, 0};
        if (kk < 4096) {
            kv = *(const uint4*)(KH + (((size_t)bh) * 4096 + kk) * 64 + spart * 8);
            vv = *(const uint4*)(VH + (((size_t)bh) * 4096 + kk) * 64 + spart * 8);
        } else if (kk < 4112) {
            kv = *(const uint4*)(Ksp + ((size_t)(b * 16 + kk - 4096)) * 512 + h * 64 + spart * 8);
            vv = *(const uint4*)(Vsp + ((size_t)(b * 16 + kk - 4096)) * 512 + h * 64 + spart * 8);
        }
        __syncthreads();   // prior PV reads done before overwriting LDS
        *(uint4*)&Klds[sr * 72 + spart * 8] = kv;
        {
            U4 u; u.v = vv;
            #pragma unroll
            for (int ii = 0; ii < 8; ++ii) Vlds[(spart * 8 + ii) * 40 + sr] = u.u[ii];
        }
        if (t < 32) {
            int k2 = key0 + t;
            float ma = -1e30f;
            if (k2 < 4096) ma = mask_t[b * 4096 + k2] ? 0.f : -1e30f;
            else if (k2 < 4112) ma = mask_s[b * 16 + k2 - 4096] ? 0.f : -1e30f;
            maskv[t] = ma;
        }
        __syncthreads();
        // ---- scores (waves 0,2): 16-key subtile each ----
        if ((wave & 1) == 0) {
            bf16x8 kf0 = *(const bf16x8*)&Klds[(sub * 16 + l16) * 72 + quad * 8];
            bf16x8 kf1 = *(const bf16x8*)&Klds[(sub * 16 + l16) * 72 + 32 + quad * 8];
            f32x4 sc = (f32x4){0.f, 0.f, 0.f, 0.f};
            sc = __builtin_amdgcn_mfma_f32_16x16x32_bf16(qf0, kf0, sc, 0, 0, 0);
            sc = __builtin_amdgcn_mfma_f32_16x16x32_bf16(qf1, kf1, sc, 0, 0, 0);
            float ma = maskv[sub * 16 + l16];
            size_t wbase = (((size_t)bh) * 16 + quad * 4) * 4112 + key0 + sub * 16 + l16;
            #pragma unroll
            for (int i = 0; i < 4; ++i) {
                float sv = sc[i] * 0.125f + ma;
                float w = __expf(sv);
                Lacc[i] += w;
                w_s[wbase + (size_t)i * 4112] = w;   // unnormalized; S4 rescales
                Plds[(quad * 4 + i) * 40 + sub * 16 + l16] = f2b(w);
            }
        }
        __syncthreads();
        // ---- PV: every wave owns a 16-wide d-tile ----
        bf16x8 pf = *(const bf16x8*)&Plds[l16 * 40 + quad * 8];
        bf16x8 vf = *(const bf16x8*)&Vlds[(d0 + l16) * 40 + quad * 8];
        pacc = __builtin_amdgcn_mfma_f32_16x16x32_bf16(pf, vf, pacc, 0, 0, 0);
    }

    // reduce L across the 16 key-lanes (waves 0,2 only)
    if ((wave & 1) == 0) {
        #pragma unroll
        for (int i = 0; i < 4; ++i) {
            float v = Lacc[i];
            v += __shfl_xor(v, 1);
            v += __shfl_xor(v, 2);
            v += __shfl_xor(v, 4);
            v += __shfl_xor(v, 8);
            Lacc[i] = v;
        }
        if (l16 == 0) {
            #pragma unroll
            for (int i = 0; i < 4; ++i) sL[wave >> 1][quad * 4 + i] = Lacc[i];
        }
    }
    // PV partials
    size_t pbase = ((size_t)(bh * 8 + c) * 16 + quad * 4) * 64 + d0 + l16;
    #pragma unroll
    for (int i = 0; i < 4; ++i) Ppart[pbase + (size_t)i * 64] = pacc[i];
    __syncthreads();
    if (t < 16) Lpart[(bh * 8 + c) * 16 + t] = sL[0][t] + sL[1][t];
}

// ---------- static attention S4: combine chunk partials + normalize ----------
__global__ __launch_bounds__(256) void static_attn_s4(
    const float* __restrict__ Ppart, const float* __restrict__ Lpart,
    float* __restrict__ w_s, unsigned short* __restrict__ qkvS)
{
    int bh = blockIdx.x, b = bh >> 3, h = bh & 7;
    __shared__ float invL[16];
    int t = threadIdx.x;
    if (t < 16) {
        float L = 0.f;
        #pragma unroll
        for (int cc = 0; cc < 8; ++cc) L += Lpart[(bh * 8 + cc) * 16 + t];
        invL[t] = 1.f / L;
    }
    __syncthreads();
    #pragma unroll
    for (int i = 0; i < 4; ++i) {
        int idx = t + i * 256;
        int q = idx >> 6, d = idx & 63;
        float s = 0.f;
        #pragma unroll
        for (int cc = 0; cc < 8; ++cc) s += Ppart[((size_t)(bh * 8 + cc) * 16 + q) * 64 + d];
        qkvS[((size_t)(b * 16 + q)) * 512 + h * 64 + d] = f2b(s * invL[q]);
    }
    size_t base = (size_t)bh * 16 * 4112;
    for (int q = 0; q < 16; ++q) {
        float il = invL[q];
        for (int kk = t; kk < 4112; kk += 256) w_s[base + q * 4112 + kk] *= il;
    }
}

// ---------- launch ----------
extern "C" void kernel_launch(void* const* d_in, const int* in_sizes, int n_in,
                              void* d_out, int out_size, void* d_ws, size_t ws_size,
                              hipStream_t stream)
{
    const float* q_t = (const float*)d_in[0];
    const float* k_t = (const float*)d_in[1];
    const float* v_t = (const float*)d_in[2];
    const float* q_s = (const float*)d_in[3];
    const float* k_s = (const float*)d_in[4];
    const float* v_s = (const float*)d_in[5];
    const int* m_t = (const int*)d_in[6];
    const int* m_s = (const int*)d_in[7];
    const float* Wq = (const float*)d_in[8];
    const float* bq = (const float*)d_in[9];
    const float* Wk = (const float*)d_in[10];
    const float* bk = (const float*)d_in[11];
    const float* Wv = (const float*)d_in[12];
    const float* bv = (const float*)d_in[13];
    const float* Wo = (const float*)d_in[14];
    const float* bo = (const float*)d_in[15];

    char* ws = (char*)d_ws;
    size_t off = 0;
    auto alloc = [&](size_t bytes) {
        void* p = ws + off;
        off += (bytes + 255) & ~(size_t)255;
        return p;
    };
    const size_t WB = (size_t)512 * 512 * 2;     // bf16 512x512
    const size_t TB = (size_t)32768 * 512 * 2;   // bf16 32768x512
    const size_t SB = (size_t)128 * 512 * 2;     // bf16 128x512
    unsigned short* WqT = (unsigned short*)alloc(WB);
    unsigned short* WkT = (unsigned short*)alloc(WB);
    unsigned short* WvT = (unsigned short*)alloc(WB);
    unsigned short* WoT = (unsigned short*)alloc(WB);
    unsigned short* Qt   = (unsigned short*)alloc(TB);  // token-major
    unsigned short* KH   = (unsigned short*)alloc(TB);  // head-major [b][h][n][d]
    unsigned short* VH   = (unsigned short*)alloc(TB);  // head-major
    unsigned short* qkvT = (unsigned short*)alloc(TB);  // token-major
    unsigned short* Qsp  = (unsigned short*)alloc(SB);
    unsigned short* Ksp  = (unsigned short*)alloc(SB);
    unsigned short* Vsp  = (unsigned short*)alloc(SB);
    unsigned short* qkvS = (unsigned short*)alloc(SB);
    float* Ppart = (float*)alloc((size_t)64 * 8 * 16 * 64 * 4);  // [bh][chunk][q][d]
    float* Lpart = (float*)alloc((size_t)64 * 8 * 16 * 4);       // [bh][chunk][q]

    float* out    = (float*)d_out;
    float* out_tp = out;                       // [8,512,8,512]
    float* w_t_o  = out + 16777216;            // [8,8,512,8,24]
    float* out_sp = out + 23068672;            // [8,16,512]
    float* w_s_o  = out + 23134208;            // [8,8,16,4112]

    transpose512cvt<<<dim3(16, 16), 256, 0, stream>>>(Wq, WqT);
    transpose512cvt<<<dim3(16, 16), 256, 0, stream>>>(Wk, WkT);
    transpose512cvt<<<dim3(16, 16), 256, 0, stream>>>(Wv, WvT);
    transpose512cvt<<<dim3(16, 16), 256, 0, stream>>>(Wo, WoT);

    gemm128<true, 1><<<dim3(256, 4), 256, 0, stream>>>(q_t, WqT, bq, Qt, 32768, 512);
    gemm128<true, 2><<<dim3(256, 4), 256, 0, stream>>>(k_t, WkT, bk, KH, 32768, 512);
    gemm128<true, 2><<<dim3(256, 4), 256, 0, stream>>>(v_t, WvT, bv, VH, 32768, 512);
    gemm128<true, 1><<<dim3(1, 4),   256, 0, stream>>>(q_s, WqT, bq, Qsp, 128, 512);
    gemm128<true, 1><<<dim3(1, 4),   256, 0, stream>>>(k_s, WkT, bk, Ksp, 128, 512);
    gemm128<true, 1><<<dim3(1, 4),   256, 0, stream>>>(v_s, WvT, bv, Vsp, 128, 512);

    temporal_attn<<<2048, 512, 0, stream>>>(Qt, KH, VH, Ksp, Vsp, m_t, m_s, w_t_o, qkvT);
    static_attn_s1<<<512, 256, 0, stream>>>(Qsp, KH, VH, Ksp, Vsp, m_t, m_s, w_s_o, Ppart, Lpart);
    static_attn_s4<<<64, 256, 0, stream>>>(Ppart, Lpart, w_s_o, qkvS);

    gemm128<false, 0><<<dim3(256, 4), 256, 0, stream>>>(qkvT, WoT, bo, out_tp, 32768, 512);
    gemm128<false, 0><<<dim3(1, 4),   256, 0, stream>>>(qkvS, WoT, bo, out_sp, 128, 512);
}

// Round 2
// 589.497 us; speedup vs baseline: 1.0527x; 1.0170x over previous
//
#include <hip/hip_runtime.h>
#include <hip/hip_bf16.h>

// ---------- helpers ----------
typedef __attribute__((ext_vector_type(8))) __bf16 bf16x8;
typedef __attribute__((ext_vector_type(4))) float f32x4;

__device__ __forceinline__ float b2f(unsigned short u) {
    unsigned int x = ((unsigned int)u) << 16;
    float f;
    __builtin_memcpy(&f, &x, 4);
    return f;
}
__device__ __forceinline__ unsigned short f2b(float f) {
    __hip_bfloat16 h = __float2bfloat16(f);
    unsigned short u;
    __builtin_memcpy(&u, &h, 2);
    return u;
}
union U4 { uint4 v; unsigned short u[8]; };

// ---------- 512x512 transpose + f32->bf16 convert (for W matrices) ----------
__global__ __launch_bounds__(256) void transpose512cvt(const float* __restrict__ in,
                                                       unsigned short* __restrict__ out)
{
    __shared__ float tile[32][33];
    int tx = threadIdx.x & 31, ty = threadIdx.x >> 5;
    int bx = blockIdx.x, by = blockIdx.y;
    #pragma unroll
    for (int i = 0; i < 32; i += 8)
        tile[ty + i][tx] = in[(size_t)(bx * 32 + ty + i) * 512 + by * 32 + tx];
    __syncthreads();
    #pragma unroll
    for (int i = 0; i < 32; i += 8)
        out[(size_t)(by * 32 + ty + i) * 512 + bx * 32 + tx] = f2b(tile[tx][ty + i]);
}

// ---------- GEMM 128x128 tile, prefetched staging: C = A[M,512] @ Bt[512,N]^T + bias ----------
// 256 threads = 4 waves in 2x2; each wave owns 64x64 = 4x4 MFMA tiles.
// K-step loads are issued at the top of the previous step's compute phase (T14
// issue-early), so MFMA + ds_read cover the global latency; the only stall left
// is the structural barrier drain. 1-D grid, n-fastest + bijective XCD chunking
// so the 4 n-blocks sharing an A panel run back-to-back on one XCD (A L2 reuse).
// CMODE: 0 = f32 token-major, 1 = bf16 token-major, 2 = bf16 head-major [b][h][n][d]
#define GPAD 40  // row stride in elems (32 + 8 pad, 80 B, 16B-aligned)

template<bool AF32, int CMODE>
__global__ __launch_bounds__(256) void gemm128(
    const void* __restrict__ Av,
    const unsigned short* __restrict__ Bt,
    const float* __restrict__ bias,
    void* __restrict__ Cv,
    int M, int N)
{
    const int K = 512;
    __shared__ __align__(16) unsigned short As[128 * GPAD];
    __shared__ __align__(16) unsigned short Bs[128 * GPAD];

    int nblk = gridDim.x, bid = blockIdx.x;
    int wid = ((nblk & 7) == 0) ? ((bid & 7) * (nblk >> 3) + (bid >> 3)) : bid;
    int nt = N >> 7;
    int m0 = (wid / nt) * 128, n0 = (wid % nt) * 128;

    int t = threadIdx.x;
    int wave = t >> 6, lane = t & 63, quad = lane >> 4, l16 = lane & 15;
    int wr = wave >> 1, wc = wave & 1;

    f32x4 acc[4][4];
    #pragma unroll
    for (int i = 0; i < 4; ++i)
        #pragma unroll
        for (int j = 0; j < 4; ++j) acc[i][j] = (f32x4){0.f, 0.f, 0.f, 0.f};

    int r = t >> 1, half = (t & 1) * 16;  // staging: row r, elems half..half+16
    const float* Ap32 = (const float*)Av + (size_t)(m0 + r) * K + half;
    const unsigned short* Ap16 = (const unsigned short*)Av + (size_t)(m0 + r) * K + half;
    const unsigned short* Bp = Bt + (size_t)(n0 + r) * K + half;

    // staging registers (single set; loads for step k+1 are issued during
    // compute of step k and consumed at the next STORE)
    float4 fa0, fa1, fa2, fa3;
    U4 ua0, ua1;
    uint4 fb0, fb1;

    auto LOADK = [&](int k0) {
        if constexpr (AF32) {
            const float4* p = (const float4*)(Ap32 + k0);
            fa0 = p[0]; fa1 = p[1]; fa2 = p[2]; fa3 = p[3];
        } else {
            ua0.v = *(const uint4*)(Ap16 + k0);
            ua1.v = *(const uint4*)(Ap16 + k0 + 8);
        }
        fb0 = *(const uint4*)(Bp + k0);
        fb1 = *(const uint4*)(Bp + k0 + 8);
    };
    auto STOREK = [&]() {
        U4 a0, a1;
        if constexpr (AF32) {
            a0.u[0]=f2b(fa0.x); a0.u[1]=f2b(fa0.y); a0.u[2]=f2b(fa0.z); a0.u[3]=f2b(fa0.w);
            a0.u[4]=f2b(fa1.x); a0.u[5]=f2b(fa1.y); a0.u[6]=f2b(fa1.z); a0.u[7]=f2b(fa1.w);
            a1.u[0]=f2b(fa2.x); a1.u[1]=f2b(fa2.y); a1.u[2]=f2b(fa2.z); a1.u[3]=f2b(fa2.w);
            a1.u[4]=f2b(fa3.x); a1.u[5]=f2b(fa3.y); a1.u[6]=f2b(fa3.z); a1.u[7]=f2b(fa3.w);
        } else {
            a0 = ua0; a1 = ua1;
        }
        *(uint4*)&As[r * GPAD + half] = a0.v;
        *(uint4*)&As[r * GPAD + half + 8] = a1.v;
        *(uint4*)&Bs[r * GPAD + half] = fb0;
        *(uint4*)&Bs[r * GPAD + half + 8] = fb1;
    };

    LOADK(0);
    for (int it = 0; it < 16; ++it) {
        __syncthreads();           // prev compute done; prefetched loads have landed
        STOREK();
        __syncthreads();           // LDS ready
        if (it < 15) LOADK((it + 1) * 32);   // issue early: MFMA below hides latency
        bf16x8 af[4], bf[4];
        #pragma unroll
        for (int i = 0; i < 4; ++i)
            af[i] = *(const bf16x8*)&As[(wr * 64 + i * 16 + l16) * GPAD + quad * 8];
        #pragma unroll
        for (int j = 0; j < 4; ++j)
            bf[j] = *(const bf16x8*)&Bs[(wc * 64 + j * 16 + l16) * GPAD + quad * 8];
        #pragma unroll
        for (int i = 0; i < 4; ++i)
            #pragma unroll
            for (int j = 0; j < 4; ++j)
                acc[i][j] = __builtin_amdgcn_mfma_f32_16x16x32_bf16(af[i], bf[j], acc[i][j], 0, 0, 0);
    }
    // epilogue. C/D layout: col = lane&15, row = quad*4 + reg
    #pragma unroll
    for (int i = 0; i < 4; ++i) {
        #pragma unroll
        for (int j = 0; j < 4; ++j) {
            int row = m0 + wr * 64 + i * 16 + quad * 4;
            int col = n0 + wc * 64 + j * 16 + l16;
            float bc = bias[col];
            #pragma unroll
            for (int ii = 0; ii < 4; ++ii) {
                float v = acc[i][j][ii] + bc;
                int R = row + ii;
                if constexpr (CMODE == 0) {
                    ((float*)Cv)[(size_t)R * N + col] = v;
                } else if constexpr (CMODE == 1) {
                    ((unsigned short*)Cv)[(size_t)R * N + col] = f2b(v);
                } else {
                    int bb = R >> 12, n = R & 4095, hh = col >> 6, d = col & 63;
                    ((unsigned short*)Cv)[(((size_t)bb * 8 + hh) * 4096 + n) * 64 + d] = f2b(v);
                }
            }
        }
    }
}

// ---------- temporal attention v2: MFMA, one block per (b, s-pair), 8 waves = 8 heads ----------
// Pair two adjacent s values -> Q tile 16x64 (rows = 2s x 8m), K tile 32x64
// (keys 0-7: s0 temporal, 8-15: s1 temporal, 16-31: static). Cross-s terms masked -inf.
// Per-wave-private LDS (V^T for PV B-operand, P round-trip) -> no barriers at all.
__global__ __launch_bounds__(512) void temporal_attn(
    const unsigned short* __restrict__ Qt, const unsigned short* __restrict__ KH,
    const unsigned short* __restrict__ VH, const unsigned short* __restrict__ Ksp,
    const unsigned short* __restrict__ Vsp,
    const int* __restrict__ mask_t, const int* __restrict__ mask_s,
    float* __restrict__ w_t_out, unsigned short* __restrict__ qkv_t)
{
    int blk = blockIdx.x;              // b*256 + sp
    int b = blk >> 8, sp = blk & 255;
    int s0 = sp * 2;
    int t = threadIdx.x;
    int h = t >> 6, lane = t & 63, quad = lane >> 4, l16 = lane & 15;

    __shared__ __align__(16) unsigned short Vt[8][64 * 40];  // per-head V^T [d][key(32)+pad]
    __shared__ __align__(16) unsigned short Pl[8][16 * 40];  // per-head P  [q][key(32)+pad]

    size_t bh = (size_t)(b * 8 + h);
    size_t tok0 = ((size_t)(b * 512 + s0)) * 8;  // first token row of the pair (rows 0..15 contiguous)

    // ---- stage V^T (wave-private; keys 0-15 temporal, 16-31 static) ----
    {
        int r = lane & 31, dh = (lane >> 5) * 32;
        const unsigned short* src = (r < 16)
            ? VH + (bh * 4096 + (size_t)(s0 * 8 + r)) * 64 + dh
            : Vsp + ((size_t)(b * 16 + (r - 16))) * 512 + h * 64 + dh;
        U4 u[4];
        #pragma unroll
        for (int g = 0; g < 4; ++g) u[g].v = ((const uint4*)src)[g];
        unsigned short* dst = &Vt[h][0];
        #pragma unroll
        for (int g = 0; g < 4; ++g)
            #pragma unroll
            for (int ii = 0; ii < 8; ++ii)
                dst[(dh + g * 8 + ii) * 40 + r] = u[g].u[ii];
    }

    // ---- Q / K fragments straight from global (row-major matches A/B fragment layout) ----
    const unsigned short* qp = Qt + (tok0 + l16) * 512 + h * 64 + quad * 8;
    bf16x8 qf0 = *(const bf16x8*)qp;
    bf16x8 qf1 = *(const bf16x8*)(qp + 32);
    const unsigned short* kpt = KH + (bh * 4096 + (size_t)(s0 * 8 + l16)) * 64 + quad * 8;
    bf16x8 kt0 = *(const bf16x8*)kpt;
    bf16x8 kt1 = *(const bf16x8*)(kpt + 32);
    const unsigned short* kps = Ksp + ((size_t)(b * 16 + l16)) * 512 + h * 64 + quad * 8;
    bf16x8 ks0 = *(const bf16x8*)kps;
    bf16x8 ks1 = *(const bf16x8*)(kps + 32);

    // ---- scores: C[row=q (quad*4+i)][col=key (l16)] ----
    f32x4 sc0 = (f32x4){0.f, 0.f, 0.f, 0.f};
    f32x4 sc1 = (f32x4){0.f, 0.f, 0.f, 0.f};
    sc0 = __builtin_amdgcn_mfma_f32_16x16x32_bf16(qf0, kt0, sc0, 0, 0, 0);
    sc0 = __builtin_amdgcn_mfma_f32_16x16x32_bf16(qf1, kt1, sc0, 0, 0, 0);
    sc1 = __builtin_amdgcn_mfma_f32_16x16x32_bf16(qf0, ks0, sc1, 0, 0, 0);
    sc1 = __builtin_amdgcn_mfma_f32_16x16x32_bf16(qf1, ks1, sc1, 0, 0, 0);

    // masks: tile0 key l16 maps linearly to token tok0+l16; cross-s block masked out.
    float madd0 = mask_t[tok0 + l16] ? 0.f : -1e30f;
    bool v0 = ((quad < 2) == (l16 < 8));   // row<8 <-> keys 0-7 (s0); row>=8 <-> keys 8-15 (s1)
    if (!v0) madd0 = -1e30f;
    float madd1 = mask_s[b * 16 + l16] ? 0.f : -1e30f;

    // ---- softmax per row (row lives entirely in one 16-lane quad group) ----
    float w0[4], w1[4];
    #pragma unroll
    for (int i = 0; i < 4; ++i) {
        float a = sc0[i] * 0.125f + madd0;
        float c = sc1[i] * 0.125f + madd1;
        float mx = fmaxf(a, c);
        mx = fmaxf(mx, __shfl_xor(mx, 1));
        mx = fmaxf(mx, __shfl_xor(mx, 2));
        mx = fmaxf(mx, __shfl_xor(mx, 4));
        mx = fmaxf(mx, __shfl_xor(mx, 8));
        float e0 = __expf(a - mx), e1 = __expf(c - mx);
        float se = e0 + e1;
        se += __shfl_xor(se, 1);
        se += __shfl_xor(se, 2);
        se += __shfl_xor(se, 4);
        se += __shfl_xor(se, 8);
        float inv = 1.f / se;
        w0[i] = e0 * inv;
        w1[i] = e1 * inv;
    }

    // ---- write w_t + stage P (wave-private LDS; masked entries are exactly 0) ----
    int row0 = quad * 4;
    #pragma unroll
    for (int i = 0; i < 4; ++i) {
        int row = row0 + i;
        Pl[h][row * 40 + l16] = f2b(w0[i]);
        Pl[h][row * 40 + 16 + l16] = f2b(w1[i]);
        int s = s0 + (row >> 3), m = row & 7;
        size_t wb = ((((size_t)b * 8 + h) * 512 + s) * 8 + m) * 24;
        if (v0) w_t_out[wb + (l16 & 7)] = w0[i];
        w_t_out[wb + 8 + l16] = w1[i];
    }

    // ---- PV: C[q][d] = P[16x32] . V[32x64]; K=32 fits one mfma k-step ----
    bf16x8 pa = *(const bf16x8*)&Pl[h][l16 * 40 + quad * 8];
    f32x4 oacc[4];
    #pragma unroll
    for (int j = 0; j < 4; ++j) {
        bf16x8 vb = *(const bf16x8*)&Vt[h][(j * 16 + l16) * 40 + quad * 8];
        oacc[j] = (f32x4){0.f, 0.f, 0.f, 0.f};
        oacc[j] = __builtin_amdgcn_mfma_f32_16x16x32_bf16(pa, vb, oacc[j], 0, 0, 0);
    }
    #pragma unroll
    for (int j = 0; j < 4; ++j)
        #pragma unroll
        for (int ii = 0; ii < 4; ++ii) {
            int row = quad * 4 + ii;
            qkv_t[(tok0 + row) * 512 + h * 64 + j * 16 + l16] = f2b(oacc[j][ii]);
        }
}

// ---------- static attention S1: fused scores + exp + PV, chunked ----------
// grid = 8 chunks x 64 (b,h). Keys processed in 32-wide steps; 129 steps total
// (step 128 = the 16 static keys). No max-subtraction (|s| <= ~8, exp safe in f32).
__global__ __launch_bounds__(256) void static_attn_s1(
    const unsigned short* __restrict__ Qsp, const unsigned short* __restrict__ KH,
    const unsigned short* __restrict__ VH, const unsigned short* __restrict__ Ksp,
    const unsigned short* __restrict__ Vsp,
    const int* __restrict__ mask_t, const int* __restrict__ mask_s,
    float* __restrict__ w_s, float* __restrict__ Ppart, float* __restrict__ Lpart)
{
    int blk = blockIdx.x;
    int bh = blk & 63, c = blk >> 6;
    int b = bh >> 3, h = bh & 7;
    __shared__ __align__(16) unsigned short Klds[32 * 72];  // [key][64] (+pad)
    __shared__ __align__(16) unsigned short Vlds[64 * 40];  // [d][key]  (+pad)
    __shared__ __align__(16) unsigned short Plds[16 * 40];  // [q][key]  (+pad)
    __shared__ float maskv[32];
    __shared__ float sL[2][16];
    int t = threadIdx.x, wave = t >> 6, lane = t & 63, quad = lane >> 4, l16 = lane & 15;

    // Q fragments (A-operand: m=l16 -> q, k=quad*8+j -> d)
    bf16x8 qf0 = *(const bf16x8*)(Qsp + ((size_t)(b * 16 + l16)) * 512 + h * 64 + quad * 8);
    bf16x8 qf1 = *(const bf16x8*)(Qsp + ((size_t)(b * 16 + l16)) * 512 + h * 64 + 32 + quad * 8);

    f32x4 pacc = (f32x4){0.f, 0.f, 0.f, 0.f};
    float Lacc[4] = {0.f, 0.f, 0.f, 0.f};
    int d0 = wave * 16;
    int sub = wave >> 1;
    int sr = t >> 3, spart = t & 7;
    int s0 = c * 16, s1 = (c == 7) ? 129 : (s0 + 16);

    for (int st = s0; st < s1; ++st) {
        int key0 = st * 32;
        // ---- stage K row-major, V transposed, masks ----
        int kk = key0 + sr;
        uint4 kv = {0, 0, 0, 0}, vv = {0, 0, 0, 0};
        if (kk < 4096) {
            kv = *(const uint4*)(KH + (((size_t)bh) * 4096 + kk) * 64 + spart * 8);
            vv = *(const uint4*)(VH + (((size_t)bh) * 4096 + kk) * 64 + spart * 8);
        } else if (kk < 4112) {
            kv = *(const uint4*)(Ksp + ((size_t)(b * 16 + kk - 4096)) * 512 + h * 64 + spart * 8);
            vv = *(const uint4*)(Vsp + ((size_t)(b * 16 + kk - 4096)) * 512 + h * 64 + spart * 8);
        }
        __syncthreads();   // prior PV reads done before overwriting LDS
        *(uint4*)&Klds[sr * 72 + spart * 8] = kv;
        {
            U4 u; u.v = vv;
            #pragma unroll
            for (int ii = 0; ii < 8; ++ii) Vlds[(spart * 8 + ii) * 40 + sr] = u.u[ii];
        }
        if (t < 32) {
            int k2 = key0 + t;
            float ma = -1e30f;
            if (k2 < 4096) ma = mask_t[b * 4096 + k2] ? 0.f : -1e30f;
            else if (k2 < 4112) ma = mask_s[b * 16 + k2 - 4096] ? 0.f : -1e30f;
            maskv[t] = ma;
        }
        __syncthreads();
        // ---- scores (waves 0,2): 16-key subtile each ----
        if ((wave & 1) == 0) {
            bf16x8 kf0 = *(const bf16x8*)&Klds[(sub * 16 + l16) * 72 + quad * 8];
            bf16x8 kf1 = *(const bf16x8*)&Klds[(sub * 16 + l16) * 72 + 32 + quad * 8];
            f32x4 sc = (f32x4){0.f, 0.f, 0.f, 0.f};
            sc = __builtin_amdgcn_mfma_f32_16x16x32_bf16(qf0, kf0, sc, 0, 0, 0);
            sc = __builtin_amdgcn_mfma_f32_16x16x32_bf16(qf1, kf1, sc, 0, 0, 0);
            float ma = maskv[sub * 16 + l16];
            size_t wbase = (((size_t)bh) * 16 + quad * 4) * 4112 + key0 + sub * 16 + l16;
            #pragma unroll
            for (int i = 0; i < 4; ++i) {
                float sv = sc[i] * 0.125f + ma;
                float w = __expf(sv);
                Lacc[i] += w;
                w_s[wbase + (size_t)i * 4112] = w;   // unnormalized; S4 rescales
                Plds[(quad * 4 + i) * 40 + sub * 16 + l16] = f2b(w);
            }
        }
        __syncthreads();
        // ---- PV: every wave owns a 16-wide d-tile ----
        bf16x8 pf = *(const bf16x8*)&Plds[l16 * 40 + quad * 8];
        bf16x8 vf = *(const bf16x8*)&Vlds[(d0 + l16) * 40 + quad * 8];
        pacc = __builtin_amdgcn_mfma_f32_16x16x32_bf16(pf, vf, pacc, 0, 0, 0);
    }

    // reduce L across the 16 key-lanes (waves 0,2 only)
    if ((wave & 1) == 0) {
        #pragma unroll
        for (int i = 0; i < 4; ++i) {
            float v = Lacc[i];
            v += __shfl_xor(v, 1);
            v += __shfl_xor(v, 2);
            v += __shfl_xor(v, 4);
            v += __shfl_xor(v, 8);
            Lacc[i] = v;
        }
        if (l16 == 0) {
            #pragma unroll
            for (int i = 0; i < 4; ++i) sL[wave >> 1][quad * 4 + i] = Lacc[i];
        }
    }
    // PV partials
    size_t pbase = ((size_t)(bh * 8 + c) * 16 + quad * 4) * 64 + d0 + l16;
    #pragma unroll
    for (int i = 0; i < 4; ++i) Ppart[pbase + (size_t)i * 64] = pacc[i];
    __syncthreads();
    if (t < 16) Lpart[(bh * 8 + c) * 16 + t] = sL[0][t] + sL[1][t];
}

// ---------- static attention S4: combine chunk partials + normalize ----------
__global__ __launch_bounds__(256) void static_attn_s4(
    const float* __restrict__ Ppart, const float* __restrict__ Lpart,
    float* __restrict__ w_s, unsigned short* __restrict__ qkvS)
{
    int bh = blockIdx.x, b = bh >> 3, h = bh & 7;
    __shared__ float invL[16];
    int t = threadIdx.x;
    if (t < 16) {
        float L = 0.f;
        #pragma unroll
        for (int cc = 0; cc < 8; ++cc) L += Lpart[(bh * 8 + cc) * 16 + t];
        invL[t] = 1.f / L;
    }
    __syncthreads();
    #pragma unroll
    for (int i = 0; i < 4; ++i) {
        int idx = t + i * 256;
        int q = idx >> 6, d = idx & 63;
        float s = 0.f;
        #pragma unroll
        for (int cc = 0; cc < 8; ++cc) s += Ppart[((size_t)(bh * 8 + cc) * 16 + q) * 64 + d];
        qkvS[((size_t)(b * 16 + q)) * 512 + h * 64 + d] = f2b(s * invL[q]);
    }
    size_t base = (size_t)bh * 16 * 4112;
    for (int q = 0; q < 16; ++q) {
        float il = invL[q];
        for (int kk = t; kk < 4112; kk += 256) w_s[base + q * 4112 + kk] *= il;
    }
}

// ---------- launch ----------
extern "C" void kernel_launch(void* const* d_in, const int* in_sizes, int n_in,
                              void* d_out, int out_size, void* d_ws, size_t ws_size,
                              hipStream_t stream)
{
    const float* q_t = (const float*)d_in[0];
    const float* k_t = (const float*)d_in[1];
    const float* v_t = (const float*)d_in[2];
    const float* q_s = (const float*)d_in[3];
    const float* k_s = (const float*)d_in[4];
    const float* v_s = (const float*)d_in[5];
    const int* m_t = (const int*)d_in[6];
    const int* m_s = (const int*)d_in[7];
    const float* Wq = (const float*)d_in[8];
    const float* bq = (const float*)d_in[9];
    const float* Wk = (const float*)d_in[10];
    const float* bk = (const float*)d_in[11];
    const float* Wv = (const float*)d_in[12];
    const float* bv = (const float*)d_in[13];
    const float* Wo = (const float*)d_in[14];
    const float* bo = (const float*)d_in[15];

    char* ws = (char*)d_ws;
    size_t off = 0;
    auto alloc = [&](size_t bytes) {
        void* p = ws + off;
        off += (bytes + 255) & ~(size_t)255;
        return p;
    };
    const size_t WB = (size_t)512 * 512 * 2;     // bf16 512x512
    const size_t TB = (size_t)32768 * 512 * 2;   // bf16 32768x512
    const size_t SB = (size_t)128 * 512 * 2;     // bf16 128x512
    unsigned short* WqT = (unsigned short*)alloc(WB);
    unsigned short* WkT = (unsigned short*)alloc(WB);
    unsigned short* WvT = (unsigned short*)alloc(WB);
    unsigned short* WoT = (unsigned short*)alloc(WB);
    unsigned short* Qt   = (unsigned short*)alloc(TB);  // token-major
    unsigned short* KH   = (unsigned short*)alloc(TB);  // head-major [b][h][n][d]
    unsigned short* VH   = (unsigned short*)alloc(TB);  // head-major
    unsigned short* qkvT = (unsigned short*)alloc(TB);  // token-major
    unsigned short* Qsp  = (unsigned short*)alloc(SB);
    unsigned short* Ksp  = (unsigned short*)alloc(SB);
    unsigned short* Vsp  = (unsigned short*)alloc(SB);
    unsigned short* qkvS = (unsigned short*)alloc(SB);
    float* Ppart = (float*)alloc((size_t)64 * 8 * 16 * 64 * 4);  // [bh][chunk][q][d]
    float* Lpart = (float*)alloc((size_t)64 * 8 * 16 * 4);       // [bh][chunk][q]

    float* out    = (float*)d_out;
    float* out_tp = out;                       // [8,512,8,512]
    float* w_t_o  = out + 16777216;            // [8,8,512,8,24]
    float* out_sp = out + 23068672;            // [8,16,512]
    float* w_s_o  = out + 23134208;            // [8,8,16,4112]

    transpose512cvt<<<dim3(16, 16), 256, 0, stream>>>(Wq, WqT);
    transpose512cvt<<<dim3(16, 16), 256, 0, stream>>>(Wk, WkT);
    transpose512cvt<<<dim3(16, 16), 256, 0, stream>>>(Wv, WvT);
    transpose512cvt<<<dim3(16, 16), 256, 0, stream>>>(Wo, WoT);

    gemm128<true, 1><<<dim3(1024), 256, 0, stream>>>(q_t, WqT, bq, Qt, 32768, 512);
    gemm128<true, 2><<<dim3(1024), 256, 0, stream>>>(k_t, WkT, bk, KH, 32768, 512);
    gemm128<true, 2><<<dim3(1024), 256, 0, stream>>>(v_t, WvT, bv, VH, 32768, 512);
    gemm128<true, 1><<<dim3(4),    256, 0, stream>>>(q_s, WqT, bq, Qsp, 128, 512);
    gemm128<true, 1><<<dim3(4),    256, 0, stream>>>(k_s, WkT, bk, Ksp, 128, 512);
    gemm128<true, 1><<<dim3(4),    256, 0, stream>>>(v_s, WvT, bv, Vsp, 128, 512);

    temporal_attn<<<2048, 512, 0, stream>>>(Qt, KH, VH, Ksp, Vsp, m_t, m_s, w_t_o, qkvT);
    static_attn_s1<<<512, 256, 0, stream>>>(Qsp, KH, VH, Ksp, Vsp, m_t, m_s, w_s_o, Ppart, Lpart);
    static_attn_s4<<<64, 256, 0, stream>>>(Ppart, Lpart, w_s_o, qkvS);

    gemm128<false, 0><<<dim3(1024), 256, 0, stream>>>(qkvT, WoT, bo, out_tp, 32768, 512);
    gemm128<false, 0><<<dim3(4),    256, 0, stream>>>(qkvS, WoT, bo, out_sp, 128, 512);
}

// Round 3
// 581.274 us; speedup vs baseline: 1.0676x; 1.0141x over previous
//
#include <hip/hip_runtime.h>
#include <hip/hip_bf16.h>

// ---------- helpers ----------
typedef __attribute__((ext_vector_type(8))) __bf16 bf16x8;
typedef __attribute__((ext_vector_type(4))) float f32x4;

__device__ __forceinline__ float b2f(unsigned short u) {
    unsigned int x = ((unsigned int)u) << 16;
    float f;
    __builtin_memcpy(&f, &x, 4);
    return f;
}
__device__ __forceinline__ unsigned short f2b(float f) {
    __hip_bfloat16 h = __float2bfloat16(f);
    unsigned short u;
    __builtin_memcpy(&u, &h, 2);
    return u;
}
union U4 { uint4 v; unsigned short u[8]; };

// ---------- 4x fused 512x512 transpose + f32->bf16 convert (W matrices) ----------
__global__ __launch_bounds__(256) void transpose512cvt4(
    const float* __restrict__ i0, const float* __restrict__ i1,
    const float* __restrict__ i2, const float* __restrict__ i3,
    unsigned short* __restrict__ o0, unsigned short* __restrict__ o1,
    unsigned short* __restrict__ o2, unsigned short* __restrict__ o3)
{
    const float* in = i0;
    unsigned short* out = o0;
    if (blockIdx.z == 1) { in = i1; out = o1; }
    else if (blockIdx.z == 2) { in = i2; out = o2; }
    else if (blockIdx.z == 3) { in = i3; out = o3; }
    __shared__ float tile[32][33];
    int tx = threadIdx.x & 31, ty = threadIdx.x >> 5;
    int bx = blockIdx.x, by = blockIdx.y;
    #pragma unroll
    for (int i = 0; i < 32; i += 8)
        tile[ty + i][tx] = in[(size_t)(bx * 32 + ty + i) * 512 + by * 32 + tx];
    __syncthreads();
    #pragma unroll
    for (int i = 0; i < 32; i += 8)
        out[(size_t)(by * 32 + ty + i) * 512 + bx * 32 + tx] = f2b(tile[tx][ty + i]);
}

// ---------- GEMM 128x128 tile: C = A[M,512] @ Bt[512,N]^T + bias ----------
// 256 threads = 4 waves in 2x2; each wave owns 64x64 = 4x4 MFMA tiles.
// Up to 3 independent GEMMs fused per launch via blockIdx.y (pointer set select).
// 2-deep ping-pong register prefetch: loads for K-step k+2 issue during compute
// of step k, so the staging store waits on a counted vmcnt, not a drain.
// cmode: 0 = f32 token-major, 1 = bf16 token-major, 2 = bf16 head-major [b][h][n][d]
#define GPAD 40  // row stride in elems (32 + 8 pad, 80 B, 16B-aligned)

struct GemmSet {
    const void* A;
    const unsigned short* B;
    const float* bias;
    void* C;
    int cmode;
};

template<bool AF32>
__global__ __launch_bounds__(256) void gemm128(
    GemmSet s0, GemmSet s1, GemmSet s2, int M, int N)
{
    GemmSet S = s0;
    if (blockIdx.y == 1) S = s1;
    else if (blockIdx.y == 2) S = s2;

    const int K = 512;
    __shared__ __align__(16) unsigned short As[128 * GPAD];
    __shared__ __align__(16) unsigned short Bs[128 * GPAD];

    int nblk = gridDim.x, bid = blockIdx.x;
    int wid = ((nblk & 7) == 0) ? ((bid & 7) * (nblk >> 3) + (bid >> 3)) : bid;
    int nt = N >> 7;
    int m0 = (wid / nt) * 128, n0 = (wid % nt) * 128;

    int t = threadIdx.x;
    int wave = t >> 6, lane = t & 63, quad = lane >> 4, l16 = lane & 15;
    int wr = wave >> 1, wc = wave & 1;

    f32x4 acc[4][4];
    #pragma unroll
    for (int i = 0; i < 4; ++i)
        #pragma unroll
        for (int j = 0; j < 4; ++j) acc[i][j] = (f32x4){0.f, 0.f, 0.f, 0.f};

    int r = t >> 1, half = (t & 1) * 16;  // staging: row r, elems half..half+16
    const float* Ap32 = (const float*)S.A + (size_t)(m0 + r) * K + half;
    const unsigned short* Ap16 = (const unsigned short*)S.A + (size_t)(m0 + r) * K + half;
    const unsigned short* Bp = S.B + (size_t)(n0 + r) * K + half;

    // two named staging register sets (static indexing -> no scratch)
    float4 fa0, fa1, fa2, fa3; U4 ua0, ua1; uint4 fb0, fb1;   // set 0
    float4 ga0, ga1, ga2, ga3; U4 va0, va1; uint4 gb0, gb1;   // set 1

    auto LOAD0 = [&](int k0) {
        if constexpr (AF32) {
            const float4* p = (const float4*)(Ap32 + k0);
            fa0 = p[0]; fa1 = p[1]; fa2 = p[2]; fa3 = p[3];
        } else {
            ua0.v = *(const uint4*)(Ap16 + k0);
            ua1.v = *(const uint4*)(Ap16 + k0 + 8);
        }
        fb0 = *(const uint4*)(Bp + k0);
        fb1 = *(const uint4*)(Bp + k0 + 8);
    };
    auto LOAD1 = [&](int k0) {
        if constexpr (AF32) {
            const float4* p = (const float4*)(Ap32 + k0);
            ga0 = p[0]; ga1 = p[1]; ga2 = p[2]; ga3 = p[3];
        } else {
            va0.v = *(const uint4*)(Ap16 + k0);
            va1.v = *(const uint4*)(Ap16 + k0 + 8);
        }
        gb0 = *(const uint4*)(Bp + k0);
        gb1 = *(const uint4*)(Bp + k0 + 8);
    };
    auto STORE0 = [&]() {
        U4 a0, a1;
        if constexpr (AF32) {
            a0.u[0]=f2b(fa0.x); a0.u[1]=f2b(fa0.y); a0.u[2]=f2b(fa0.z); a0.u[3]=f2b(fa0.w);
            a0.u[4]=f2b(fa1.x); a0.u[5]=f2b(fa1.y); a0.u[6]=f2b(fa1.z); a0.u[7]=f2b(fa1.w);
            a1.u[0]=f2b(fa2.x); a1.u[1]=f2b(fa2.y); a1.u[2]=f2b(fa2.z); a1.u[3]=f2b(fa2.w);
            a1.u[4]=f2b(fa3.x); a1.u[5]=f2b(fa3.y); a1.u[6]=f2b(fa3.z); a1.u[7]=f2b(fa3.w);
        } else { a0 = ua0; a1 = ua1; }
        *(uint4*)&As[r * GPAD + half] = a0.v;
        *(uint4*)&As[r * GPAD + half + 8] = a1.v;
        *(uint4*)&Bs[r * GPAD + half] = fb0;
        *(uint4*)&Bs[r * GPAD + half + 8] = fb1;
    };
    auto STORE1 = [&]() {
        U4 a0, a1;
        if constexpr (AF32) {
            a0.u[0]=f2b(ga0.x); a0.u[1]=f2b(ga0.y); a0.u[2]=f2b(ga0.z); a0.u[3]=f2b(ga0.w);
            a0.u[4]=f2b(ga1.x); a0.u[5]=f2b(ga1.y); a0.u[6]=f2b(ga1.z); a0.u[7]=f2b(ga1.w);
            a1.u[0]=f2b(ga2.x); a1.u[1]=f2b(ga2.y); a1.u[2]=f2b(ga2.z); a1.u[3]=f2b(ga2.w);
            a1.u[4]=f2b(ga3.x); a1.u[5]=f2b(ga3.y); a1.u[6]=f2b(ga3.z); a1.u[7]=f2b(ga3.w);
        } else { a0 = va0; a1 = va1; }
        *(uint4*)&As[r * GPAD + half] = a0.v;
        *(uint4*)&As[r * GPAD + half + 8] = a1.v;
        *(uint4*)&Bs[r * GPAD + half] = gb0;
        *(uint4*)&Bs[r * GPAD + half + 8] = gb1;
    };
    auto COMPUTE = [&]() {
        bf16x8 af[4], bf[4];
        #pragma unroll
        for (int i = 0; i < 4; ++i)
            af[i] = *(const bf16x8*)&As[(wr * 64 + i * 16 + l16) * GPAD + quad * 8];
        #pragma unroll
        for (int j = 0; j < 4; ++j)
            bf[j] = *(const bf16x8*)&Bs[(wc * 64 + j * 16 + l16) * GPAD + quad * 8];
        #pragma unroll
        for (int i = 0; i < 4; ++i)
            #pragma unroll
            for (int j = 0; j < 4; ++j)
                acc[i][j] = __builtin_amdgcn_mfma_f32_16x16x32_bf16(af[i], bf[j], acc[i][j], 0, 0, 0);
    };

    LOAD0(0);
    LOAD1(32);
    for (int it = 0; it < 16; it += 2) {
        __syncthreads();                       // LDS free (prev compute done)
        STORE0();                              // waits only on set-0 loads (counted)
        __syncthreads();                       // LDS ready
        if (it + 2 < 16) LOAD0((it + 2) * 32); // issue 2 steps ahead
        COMPUTE();
        __syncthreads();
        STORE1();
        __syncthreads();
        if (it + 3 < 16) LOAD1((it + 3) * 32);
        COMPUTE();
    }

    // epilogue. C/D layout: col = lane&15, row = quad*4 + reg
    int cmode = S.cmode;
    #pragma unroll
    for (int i = 0; i < 4; ++i) {
        #pragma unroll
        for (int j = 0; j < 4; ++j) {
            int row = m0 + wr * 64 + i * 16 + quad * 4;
            int col = n0 + wc * 64 + j * 16 + l16;
            float bc = S.bias[col];
            #pragma unroll
            for (int ii = 0; ii < 4; ++ii) {
                float v = acc[i][j][ii] + bc;
                int R = row + ii;
                if (cmode == 0) {
                    ((float*)S.C)[(size_t)R * N + col] = v;
                } else if (cmode == 1) {
                    ((unsigned short*)S.C)[(size_t)R * N + col] = f2b(v);
                } else {
                    int bb = R >> 12, n = R & 4095, hh = col >> 6, d = col & 63;
                    ((unsigned short*)S.C)[(((size_t)bb * 8 + hh) * 4096 + n) * 64 + d] = f2b(v);
                }
            }
        }
    }
}

// ---------- temporal attention v2: MFMA, one block per (b, s-pair), 8 waves = 8 heads ----------
// Pair two adjacent s values -> Q tile 16x64 (rows = 2s x 8m), K tile 32x64
// (keys 0-7: s0 temporal, 8-15: s1 temporal, 16-31: static). Cross-s terms masked -inf.
// Per-wave-private LDS (V^T for PV B-operand, P round-trip) -> no barriers at all.
__global__ __launch_bounds__(512) void temporal_attn(
    const unsigned short* __restrict__ Qt, const unsigned short* __restrict__ KH,
    const unsigned short* __restrict__ VH, const unsigned short* __restrict__ Ksp,
    const unsigned short* __restrict__ Vsp,
    const int* __restrict__ mask_t, const int* __restrict__ mask_s,
    float* __restrict__ w_t_out, unsigned short* __restrict__ qkv_t)
{
    int blk = blockIdx.x;              // b*256 + sp
    int b = blk >> 8, sp = blk & 255;
    int s0 = sp * 2;
    int t = threadIdx.x;
    int h = t >> 6, lane = t & 63, quad = lane >> 4, l16 = lane & 15;

    __shared__ __align__(16) unsigned short Vt[8][64 * 40];  // per-head V^T [d][key(32)+pad]
    __shared__ __align__(16) unsigned short Pl[8][16 * 40];  // per-head P  [q][key(32)+pad]

    size_t bh = (size_t)(b * 8 + h);
    size_t tok0 = ((size_t)(b * 512 + s0)) * 8;  // first token row of the pair (rows 0..15 contiguous)

    // ---- stage V^T (wave-private; keys 0-15 temporal, 16-31 static) ----
    {
        int r = lane & 31, dh = (lane >> 5) * 32;
        const unsigned short* src = (r < 16)
            ? VH + (bh * 4096 + (size_t)(s0 * 8 + r)) * 64 + dh
            : Vsp + ((size_t)(b * 16 + (r - 16))) * 512 + h * 64 + dh;
        U4 u[4];
        #pragma unroll
        for (int g = 0; g < 4; ++g) u[g].v = ((const uint4*)src)[g];
        unsigned short* dst = &Vt[h][0];
        #pragma unroll
        for (int g = 0; g < 4; ++g)
            #pragma unroll
            for (int ii = 0; ii < 8; ++ii)
                dst[(dh + g * 8 + ii) * 40 + r] = u[g].u[ii];
    }

    // ---- Q / K fragments straight from global (row-major matches A/B fragment layout) ----
    const unsigned short* qp = Qt + (tok0 + l16) * 512 + h * 64 + quad * 8;
    bf16x8 qf0 = *(const bf16x8*)qp;
    bf16x8 qf1 = *(const bf16x8*)(qp + 32);
    const unsigned short* kpt = KH + (bh * 4096 + (size_t)(s0 * 8 + l16)) * 64 + quad * 8;
    bf16x8 kt0 = *(const bf16x8*)kpt;
    bf16x8 kt1 = *(const bf16x8*)(kpt + 32);
    const unsigned short* kps = Ksp + ((size_t)(b * 16 + l16)) * 512 + h * 64 + quad * 8;
    bf16x8 ks0 = *(const bf16x8*)kps;
    bf16x8 ks1 = *(const bf16x8*)(kps + 32);

    // ---- scores: C[row=q (quad*4+i)][col=key (l16)] ----
    f32x4 sc0 = (f32x4){0.f, 0.f, 0.f, 0.f};
    f32x4 sc1 = (f32x4){0.f, 0.f, 0.f, 0.f};
    sc0 = __builtin_amdgcn_mfma_f32_16x16x32_bf16(qf0, kt0, sc0, 0, 0, 0);
    sc0 = __builtin_amdgcn_mfma_f32_16x16x32_bf16(qf1, kt1, sc0, 0, 0, 0);
    sc1 = __builtin_amdgcn_mfma_f32_16x16x32_bf16(qf0, ks0, sc1, 0, 0, 0);
    sc1 = __builtin_amdgcn_mfma_f32_16x16x32_bf16(qf1, ks1, sc1, 0, 0, 0);

    // masks: tile0 key l16 maps linearly to token tok0+l16; cross-s block masked out.
    float madd0 = mask_t[tok0 + l16] ? 0.f : -1e30f;
    bool v0 = ((quad < 2) == (l16 < 8));   // row<8 <-> keys 0-7 (s0); row>=8 <-> keys 8-15 (s1)
    if (!v0) madd0 = -1e30f;
    float madd1 = mask_s[b * 16 + l16] ? 0.f : -1e30f;

    // ---- softmax per row (row lives entirely in one 16-lane quad group) ----
    float w0[4], w1[4];
    #pragma unroll
    for (int i = 0; i < 4; ++i) {
        float a = sc0[i] * 0.125f + madd0;
        float c = sc1[i] * 0.125f + madd1;
        float mx = fmaxf(a, c);
        mx = fmaxf(mx, __shfl_xor(mx, 1));
        mx = fmaxf(mx, __shfl_xor(mx, 2));
        mx = fmaxf(mx, __shfl_xor(mx, 4));
        mx = fmaxf(mx, __shfl_xor(mx, 8));
        float e0 = __expf(a - mx), e1 = __expf(c - mx);
        float se = e0 + e1;
        se += __shfl_xor(se, 1);
        se += __shfl_xor(se, 2);
        se += __shfl_xor(se, 4);
        se += __shfl_xor(se, 8);
        float inv = 1.f / se;
        w0[i] = e0 * inv;
        w1[i] = e1 * inv;
    }

    // ---- write w_t + stage P (wave-private LDS; masked entries are exactly 0) ----
    int row0 = quad * 4;
    #pragma unroll
    for (int i = 0; i < 4; ++i) {
        int row = row0 + i;
        Pl[h][row * 40 + l16] = f2b(w0[i]);
        Pl[h][row * 40 + 16 + l16] = f2b(w1[i]);
        int s = s0 + (row >> 3), m = row & 7;
        size_t wb = ((((size_t)b * 8 + h) * 512 + s) * 8 + m) * 24;
        if (v0) w_t_out[wb + (l16 & 7)] = w0[i];
        w_t_out[wb + 8 + l16] = w1[i];
    }

    // ---- PV: C[q][d] = P[16x32] . V[32x64]; K=32 fits one mfma k-step ----
    bf16x8 pa = *(const bf16x8*)&Pl[h][l16 * 40 + quad * 8];
    f32x4 oacc[4];
    #pragma unroll
    for (int j = 0; j < 4; ++j) {
        bf16x8 vb = *(const bf16x8*)&Vt[h][(j * 16 + l16) * 40 + quad * 8];
        oacc[j] = (f32x4){0.f, 0.f, 0.f, 0.f};
        oacc[j] = __builtin_amdgcn_mfma_f32_16x16x32_bf16(pa, vb, oacc[j], 0, 0, 0);
    }
    #pragma unroll
    for (int j = 0; j < 4; ++j)
        #pragma unroll
        for (int ii = 0; ii < 4; ++ii) {
            int row = quad * 4 + ii;
            qkv_t[(tok0 + row) * 512 + h * 64 + j * 16 + l16] = f2b(oacc[j][ii]);
        }
}

// ---------- static attention S1: fused scores + exp + PV, chunked ----------
// grid = 8 chunks x 64 (b,h). Keys processed in 32-wide steps; 129 steps total
// (step 128 = the 16 static keys). No max-subtraction (|s| <= ~8, exp safe in f32).
__global__ __launch_bounds__(256) void static_attn_s1(
    const unsigned short* __restrict__ Qsp, const unsigned short* __restrict__ KH,
    const unsigned short* __restrict__ VH, const unsigned short* __restrict__ Ksp,
    const unsigned short* __restrict__ Vsp,
    const int* __restrict__ mask_t, const int* __restrict__ mask_s,
    float* __restrict__ w_s, float* __restrict__ Ppart, float* __restrict__ Lpart)
{
    int blk = blockIdx.x;
    int bh = blk & 63, c = blk >> 6;
    int b = bh >> 3, h = bh & 7;
    __shared__ __align__(16) unsigned short Klds[32 * 72];  // [key][64] (+pad)
    __shared__ __align__(16) unsigned short Vlds[64 * 40];  // [d][key]  (+pad)
    __shared__ __align__(16) unsigned short Plds[16 * 40];  // [q][key]  (+pad)
    __shared__ float maskv[32];
    __shared__ float sL[2][16];
    int t = threadIdx.x, wave = t >> 6, lane = t & 63, quad = lane >> 4, l16 = lane & 15;

    // Q fragments (A-operand: m=l16 -> q, k=quad*8+j -> d)
    bf16x8 qf0 = *(const bf16x8*)(Qsp + ((size_t)(b * 16 + l16)) * 512 + h * 64 + quad * 8);
    bf16x8 qf1 = *(const bf16x8*)(Qsp + ((size_t)(b * 16 + l16)) * 512 + h * 64 + 32 + quad * 8);

    f32x4 pacc = (f32x4){0.f, 0.f, 0.f, 0.f};
    float Lacc[4] = {0.f, 0.f, 0.f, 0.f};
    int d0 = wave * 16;
    int sub = wave >> 1;
    int sr = t >> 3, spart = t & 7;
    int s0 = c * 16, s1 = (c == 7) ? 129 : (s0 + 16);

    for (int st = s0; st < s1; ++st) {
        int key0 = st * 32;
        // ---- stage K row-major, V transposed, masks ----
        int kk = key0 + sr;
        uint4 kv = {0, 0, 0, 0}, vv = {0, 0, 0, 0};
        if (kk < 4096) {
            kv = *(const uint4*)(KH + (((size_t)bh) * 4096 + kk) * 64 + spart * 8);
            vv = *(const uint4*)(VH + (((size_t)bh) * 4096 + kk) * 64 + spart * 8);
        } else if (kk < 4112) {
            kv = *(const uint4*)(Ksp + ((size_t)(b * 16 + kk - 4096)) * 512 + h * 64 + spart * 8);
            vv = *(const uint4*)(Vsp + ((size_t)(b * 16 + kk - 4096)) * 512 + h * 64 + spart * 8);
        }
        __syncthreads();   // prior PV reads done before overwriting LDS
        *(uint4*)&Klds[sr * 72 + spart * 8] = kv;
        {
            U4 u; u.v = vv;
            #pragma unroll
            for (int ii = 0; ii < 8; ++ii) Vlds[(spart * 8 + ii) * 40 + sr] = u.u[ii];
        }
        if (t < 32) {
            int k2 = key0 + t;
            float ma = -1e30f;
            if (k2 < 4096) ma = mask_t[b * 4096 + k2] ? 0.f : -1e30f;
            else if (k2 < 4112) ma = mask_s[b * 16 + k2 - 4096] ? 0.f : -1e30f;
            maskv[t] = ma;
        }
        __syncthreads();
        // ---- scores (waves 0,2): 16-key subtile each ----
        if ((wave & 1) == 0) {
            bf16x8 kf0 = *(const bf16x8*)&Klds[(sub * 16 + l16) * 72 + quad * 8];
            bf16x8 kf1 = *(const bf16x8*)&Klds[(sub * 16 + l16) * 72 + 32 + quad * 8];
            f32x4 sc = (f32x4){0.f, 0.f, 0.f, 0.f};
            sc = __builtin_amdgcn_mfma_f32_16x16x32_bf16(qf0, kf0, sc, 0, 0, 0);
            sc = __builtin_amdgcn_mfma_f32_16x16x32_bf16(qf1, kf1, sc, 0, 0, 0);
            float ma = maskv[sub * 16 + l16];
            size_t wbase = (((size_t)bh) * 16 + quad * 4) * 4112 + key0 + sub * 16 + l16;
            #pragma unroll
            for (int i = 0; i < 4; ++i) {
                float sv = sc[i] * 0.125f + ma;
                float w = __expf(sv);
                Lacc[i] += w;
                w_s[wbase + (size_t)i * 4112] = w;   // unnormalized; S4 rescales
                Plds[(quad * 4 + i) * 40 + sub * 16 + l16] = f2b(w);
            }
        }
        __syncthreads();
        // ---- PV: every wave owns a 16-wide d-tile ----
        bf16x8 pf = *(const bf16x8*)&Plds[l16 * 40 + quad * 8];
        bf16x8 vf = *(const bf16x8*)&Vlds[(d0 + l16) * 40 + quad * 8];
        pacc = __builtin_amdgcn_mfma_f32_16x16x32_bf16(pf, vf, pacc, 0, 0, 0);
    }

    // reduce L across the 16 key-lanes (waves 0,2 only)
    if ((wave & 1) == 0) {
        #pragma unroll
        for (int i = 0; i < 4; ++i) {
            float v = Lacc[i];
            v += __shfl_xor(v, 1);
            v += __shfl_xor(v, 2);
            v += __shfl_xor(v, 4);
            v += __shfl_xor(v, 8);
            Lacc[i] = v;
        }
        if (l16 == 0) {
            #pragma unroll
            for (int i = 0; i < 4; ++i) sL[wave >> 1][quad * 4 + i] = Lacc[i];
        }
    }
    // PV partials
    size_t pbase = ((size_t)(bh * 8 + c) * 16 + quad * 4) * 64 + d0 + l16;
    #pragma unroll
    for (int i = 0; i < 4; ++i) Ppart[pbase + (size_t)i * 64] = pacc[i];
    __syncthreads();
    if (t < 16) Lpart[(bh * 8 + c) * 16 + t] = sL[0][t] + sL[1][t];
}

// ---------- static attention S4: combine chunk partials + normalize ----------
__global__ __launch_bounds__(256) void static_attn_s4(
    const float* __restrict__ Ppart, const float* __restrict__ Lpart,
    float* __restrict__ w_s, unsigned short* __restrict__ qkvS)
{
    int bh = blockIdx.x, b = bh >> 3, h = bh & 7;
    __shared__ float invL[16];
    int t = threadIdx.x;
    if (t < 16) {
        float L = 0.f;
        #pragma unroll
        for (int cc = 0; cc < 8; ++cc) L += Lpart[(bh * 8 + cc) * 16 + t];
        invL[t] = 1.f / L;
    }
    __syncthreads();
    #pragma unroll
    for (int i = 0; i < 4; ++i) {
        int idx = t + i * 256;
        int q = idx >> 6, d = idx & 63;
        float s = 0.f;
        #pragma unroll
        for (int cc = 0; cc < 8; ++cc) s += Ppart[((size_t)(bh * 8 + cc) * 16 + q) * 64 + d];
        qkvS[((size_t)(b * 16 + q)) * 512 + h * 64 + d] = f2b(s * invL[q]);
    }
    size_t base = (size_t)bh * 16 * 4112;
    for (int q = 0; q < 16; ++q) {
        float il = invL[q];
        for (int kk = t; kk < 4112; kk += 256) w_s[base + q * 4112 + kk] *= il;
    }
}

// ---------- launch ----------
extern "C" void kernel_launch(void* const* d_in, const int* in_sizes, int n_in,
                              void* d_out, int out_size, void* d_ws, size_t ws_size,
                              hipStream_t stream)
{
    const float* q_t = (const float*)d_in[0];
    const float* k_t = (const float*)d_in[1];
    const float* v_t = (const float*)d_in[2];
    const float* q_s = (const float*)d_in[3];
    const float* k_s = (const float*)d_in[4];
    const float* v_s = (const float*)d_in[5];
    const int* m_t = (const int*)d_in[6];
    const int* m_s = (const int*)d_in[7];
    const float* Wq = (const float*)d_in[8];
    const float* bq = (const float*)d_in[9];
    const float* Wk = (const float*)d_in[10];
    const float* bk = (const float*)d_in[11];
    const float* Wv = (const float*)d_in[12];
    const float* bv = (const float*)d_in[13];
    const float* Wo = (const float*)d_in[14];
    const float* bo = (const float*)d_in[15];

    char* ws = (char*)d_ws;
    size_t off = 0;
    auto alloc = [&](size_t bytes) {
        void* p = ws + off;
        off += (bytes + 255) & ~(size_t)255;
        return p;
    };
    const size_t WB = (size_t)512 * 512 * 2;     // bf16 512x512
    const size_t TB = (size_t)32768 * 512 * 2;   // bf16 32768x512
    const size_t SB = (size_t)128 * 512 * 2;     // bf16 128x512
    unsigned short* WqT = (unsigned short*)alloc(WB);
    unsigned short* WkT = (unsigned short*)alloc(WB);
    unsigned short* WvT = (unsigned short*)alloc(WB);
    unsigned short* WoT = (unsigned short*)alloc(WB);
    unsigned short* Qt   = (unsigned short*)alloc(TB);  // token-major
    unsigned short* KH   = (unsigned short*)alloc(TB);  // head-major [b][h][n][d]
    unsigned short* VH   = (unsigned short*)alloc(TB);  // head-major
    unsigned short* qkvT = (unsigned short*)alloc(TB);  // token-major
    unsigned short* Qsp  = (unsigned short*)alloc(SB);
    unsigned short* Ksp  = (unsigned short*)alloc(SB);
    unsigned short* Vsp  = (unsigned short*)alloc(SB);
    unsigned short* qkvS = (unsigned short*)alloc(SB);
    float* Ppart = (float*)alloc((size_t)64 * 8 * 16 * 64 * 4);  // [bh][chunk][q][d]
    float* Lpart = (float*)alloc((size_t)64 * 8 * 16 * 4);       // [bh][chunk][q]

    float* out    = (float*)d_out;
    float* out_tp = out;                       // [8,512,8,512]
    float* w_t_o  = out + 16777216;            // [8,8,512,8,24]
    float* out_sp = out + 23068672;            // [8,16,512]
    float* w_s_o  = out + 23134208;            // [8,8,16,4112]

    transpose512cvt4<<<dim3(16, 16, 4), 256, 0, stream>>>(Wq, Wk, Wv, Wo, WqT, WkT, WvT, WoT);

    GemmSet gq  = { q_t,  WqT, bq, Qt,   1 };
    GemmSet gk  = { k_t,  WkT, bk, KH,   2 };
    GemmSet gv  = { v_t,  WvT, bv, VH,   2 };
    GemmSet gqs = { q_s,  WqT, bq, Qsp,  1 };
    GemmSet gks = { k_s,  WkT, bk, Ksp,  1 };
    GemmSet gvs = { v_s,  WvT, bv, Vsp,  1 };
    GemmSet got = { qkvT, WoT, bo, out_tp, 0 };
    GemmSet gos = { qkvS, WoT, bo, out_sp, 0 };

    gemm128<true><<<dim3(1024, 3), 256, 0, stream>>>(gq, gk, gv, 32768, 512);
    gemm128<true><<<dim3(4, 3),    256, 0, stream>>>(gqs, gks, gvs, 128, 512);

    temporal_attn<<<2048, 512, 0, stream>>>(Qt, KH, VH, Ksp, Vsp, m_t, m_s, w_t_o, qkvT);
    static_attn_s1<<<512, 256, 0, stream>>>(Qsp, KH, VH, Ksp, Vsp, m_t, m_s, w_s_o, Ppart, Lpart);
    static_attn_s4<<<64, 256, 0, stream>>>(Ppart, Lpart, w_s_o, qkvS);

    gemm128<false><<<dim3(1024, 1), 256, 0, stream>>>(got, got, got, 32768, 512);
    gemm128<false><<<dim3(4, 1),    256, 0, stream>>>(gos, gos, gos, 128, 512);
}